// Round 1
// baseline (510.971 us; speedup 1.0000x reference)
//
#include <hip/hip_runtime.h>
#include <stdint.h>

// Self-attention, B=8, S=2048, D=1024, fp32 in/out, bf16 MFMA compute.
//
// Pipeline (all on `stream`):
//   1. cvt: x -> xb (bf16), Wq/Wk/Wv -> Wb (bf16, contiguous)
//   2. k_qkv  : Q/K/V = xb @ W^T + b          (GEMM_BT, grid.z=3, bf16 out)
//   3. k_trans: Vt[b][d][s] = V[b][s][d]      (so PV is K-contiguous GEMM_BT)
//   4. k_scores: U = exp((Q @ K^T)/32)        (bf16, no max-subtraction: scores
//                                              bounded |s|<=|q||k|/32 ~ O(10))
//   5. k_rowsum: linv[b,m] = 1 / sum_k U      (deterministic block reduce)
//   6. k_pv   : out = (U @ Vt^T) * linv       (fp32 out)
//
// ws layout (bytes):
//   [0,       33.5M)  Q        16384x1024 bf16
//   [33.5M,   67.1M)  K        16384x1024 bf16
//   [67.1M,  100.7M)  Vt       8 x 1024x2048 bf16
//   [100.7M, 167.8M)  U        8 x 2048x2048 bf16
//        first half aliases xb (dead after k_qkv), second half aliases V
//        (dead after k_trans) -- k_scores overwrites both, legally.
//   [167.8M, 174.1M)  Wb       3 x 1024x1024 bf16
//   [174.1M, ...)     linv     16384 fp32
// Total ~174.1 MB.

typedef __bf16 bf16_t;
typedef __bf16 bf16x8 __attribute__((ext_vector_type(8)));
typedef __bf16 bf16x4 __attribute__((ext_vector_type(4)));
typedef float f32x4 __attribute__((ext_vector_type(4)));

__device__ __forceinline__ void gload_lds16(const bf16_t* g, bf16_t* l) {
    // async global->LDS, 16B per lane; LDS dest must be wave-uniform base + lane*16
    __builtin_amdgcn_global_load_lds((const __attribute__((address_space(1))) void*)g,
                                     (__attribute__((address_space(3))) void*)l,
                                     16, 0, 0);
}

// ---------------------------------------------------------------------------
// Core GEMM: C[M,N] = A[M,K] @ B[N,K]^T, both A,B bf16 row-major K-contiguous.
// Tile: 128x128, BK=64, 256 threads (4 waves, 2x2), 4x4 16x16x32 MFMAs/wave.
// EPI: 0 = +bias[col] -> bf16   (aux = bias, fp32)
//      1 = exp(acc*scale) -> bf16
//      2 = acc*aux[row] -> fp32  (aux = 1/l per row)
// M,N implied by grid (y = M/128, x = N/128). All dims divide 128/64 exactly.
// ---------------------------------------------------------------------------
template <int EPI>
__device__ __forceinline__ void gemm_bt_core(
    const bf16_t* __restrict__ A, int lda,
    const bf16_t* __restrict__ B, int ldb,
    bf16_t* __restrict__ Cb, float* __restrict__ Cf, int ldc,
    const float* __restrict__ aux, float scale, int K)
{
    __shared__ bf16_t As[128 * 64];
    __shared__ bf16_t Bs[128 * 64];

    const int t    = threadIdx.x;
    const int lane = t & 63;
    const int wave = t >> 6;
    const int wm   = wave >> 1;        // wave row (0..1) -> 64 rows
    const int wn   = wave & 1;         // wave col (0..1) -> 64 cols
    const int lr   = lane & 15;
    const int quad = lane >> 4;
    const int m0   = blockIdx.y * 128;
    const int n0   = blockIdx.x * 128;

    // staging: thread t covers (row = t/8 + j*32, elems (t%8)*8 .. +8)
    const int srow   = t >> 3;
    const int schunk = (t & 7) * 8;

    f32x4 acc[4][4];
#pragma unroll
    for (int i = 0; i < 4; i++)
#pragma unroll
        for (int j = 0; j < 4; j++) acc[i][j] = (f32x4){0.f, 0.f, 0.f, 0.f};

    const bf16_t* Ag = A + (size_t)(m0 + srow) * lda + schunk;
    const bf16_t* Bg = B + (size_t)(n0 + srow) * ldb + schunk;

    for (int kt = 0; kt < K; kt += 64) {
#pragma unroll
        for (int j = 0; j < 4; j++) {
            gload_lds16(Ag + (size_t)j * 32 * lda + kt, As + j * 2048 + t * 8);
            gload_lds16(Bg + (size_t)j * 32 * ldb + kt, Bs + j * 2048 + t * 8);
        }
        __syncthreads();   // compiler drains vmcnt(0) before s_barrier

#pragma unroll
        for (int s = 0; s < 2; s++) {
            bf16x8 af[4], bfr[4];
#pragma unroll
            for (int i = 0; i < 4; i++)
                af[i] = *(const bf16x8*)(As + (wm * 64 + i * 16 + lr) * 64 + s * 32 + quad * 8);
#pragma unroll
            for (int j = 0; j < 4; j++)
                bfr[j] = *(const bf16x8*)(Bs + (wn * 64 + j * 16 + lr) * 64 + s * 32 + quad * 8);
#pragma unroll
            for (int i = 0; i < 4; i++)
#pragma unroll
                for (int j = 0; j < 4; j++)
                    acc[i][j] = __builtin_amdgcn_mfma_f32_16x16x32_bf16(af[i], bfr[j], acc[i][j], 0, 0, 0);
        }
        __syncthreads();
    }

    // Epilogue. C/D layout: col = lane&15, row = quad*4 + reg.
    if (EPI == 0) {
#pragma unroll
        for (int j = 0; j < 4; j++) {
            const int col  = n0 + wn * 64 + j * 16 + lr;
            const float bv = aux[col];
#pragma unroll
            for (int i = 0; i < 4; i++) {
                const int row = m0 + wm * 64 + i * 16 + quad * 4;
#pragma unroll
                for (int r = 0; r < 4; r++)
                    Cb[(size_t)(row + r) * ldc + col] = (__bf16)(acc[i][j][r] + bv);
            }
        }
    } else if (EPI == 1) {
#pragma unroll
        for (int j = 0; j < 4; j++) {
            const int col = n0 + wn * 64 + j * 16 + lr;
#pragma unroll
            for (int i = 0; i < 4; i++) {
                const int row = m0 + wm * 64 + i * 16 + quad * 4;
#pragma unroll
                for (int r = 0; r < 4; r++)
                    Cb[(size_t)(row + r) * ldc + col] = (__bf16)__expf(acc[i][j][r] * scale);
            }
        }
    } else {
#pragma unroll
        for (int i = 0; i < 4; i++) {
            const int row = m0 + wm * 64 + i * 16 + quad * 4;
#pragma unroll
            for (int r = 0; r < 4; r++) {
                const float s = aux[row + r];
                float* crow = Cf + (size_t)(row + r) * ldc + n0 + wn * 64 + lr;
#pragma unroll
                for (int j = 0; j < 4; j++)
                    crow[j * 16] = acc[i][0][r] * 0.f + acc[i][j][r] * s; // keep simple: acc*s
            }
        }
    }
}

// --------------------------- kernel wrappers -------------------------------

__global__ __launch_bounds__(256) void k_qkv(
    const bf16_t* __restrict__ xb, const bf16_t* __restrict__ Wb,
    bf16_t* __restrict__ Q, bf16_t* __restrict__ V,
    const float* __restrict__ bq, const float* __restrict__ bk,
    const float* __restrict__ bv)
{
    const int z = blockIdx.z;
    const float* bias = (z == 0) ? bq : (z == 1) ? bk : bv;
    bf16_t* C = (z == 2) ? V : Q + (size_t)z * 16384 * 1024;
    gemm_bt_core<0>(xb, 1024, Wb + (size_t)z * 1024 * 1024, 1024,
                    C, nullptr, 1024, bias, 0.f, 1024);
}

__global__ __launch_bounds__(256) void k_scores(
    const bf16_t* __restrict__ Q, const bf16_t* __restrict__ Km,
    bf16_t* __restrict__ U)
{
    const int b = blockIdx.z;
    gemm_bt_core<1>(Q + (size_t)b * 2048 * 1024, 1024,
                    Km + (size_t)b * 2048 * 1024, 1024,
                    U + (size_t)b * 2048 * 2048, nullptr, 2048,
                    nullptr, 0.03125f, 1024);
}

__global__ __launch_bounds__(256) void k_pv(
    const bf16_t* __restrict__ U, const bf16_t* __restrict__ Vt,
    float* __restrict__ Out, const float* __restrict__ linv)
{
    const int b = blockIdx.z;
    gemm_bt_core<2>(U + (size_t)b * 2048 * 2048, 2048,
                    Vt + (size_t)b * 1024 * 2048, 2048,
                    nullptr, Out + (size_t)b * 2048 * 1024, 1024,
                    linv + b * 2048, 0.f, 2048);
}

// fp32 -> bf16 conversion, 4 elems/thread, grid-stride
__global__ __launch_bounds__(256) void k_cvt(
    const float* __restrict__ in, bf16_t* __restrict__ out, long ngroups)
{
    long idx    = (long)blockIdx.x * blockDim.x + threadIdx.x;
    long stride = (long)gridDim.x * blockDim.x;
    for (long i = idx; i < ngroups; i += stride) {
        float4 v = ((const float4*)in)[i];
        bf16x4 o = { (__bf16)v.x, (__bf16)v.y, (__bf16)v.z, (__bf16)v.w };
        ((bf16x4*)out)[i] = o;
    }
}

// V (8 x 2048 x 1024) -> Vt (8 x 1024 x 2048), 64x64 LDS tiles
__global__ __launch_bounds__(256) void k_trans(
    const bf16_t* __restrict__ V, bf16_t* __restrict__ Vt)
{
    __shared__ bf16_t tile[64][66];
    const int b  = blockIdx.z;
    const int d0 = blockIdx.x * 64;
    const int s0 = blockIdx.y * 64;
    const bf16_t* Vb = V + (size_t)b * 2048 * 1024;
    bf16_t* Vtb      = Vt + (size_t)b * 1024 * 2048;
    const int t = threadIdx.x;

#pragma unroll
    for (int j = 0; j < 2; j++) {
        const int r = j * 32 + (t >> 3);
        const int c = (t & 7) * 8;
        bf16x8 v = *(const bf16x8*)(Vb + (size_t)(s0 + r) * 1024 + d0 + c);
#pragma unroll
        for (int e = 0; e < 8; e++) tile[r][c + e] = v[e];
    }
    __syncthreads();
#pragma unroll
    for (int j = 0; j < 2; j++) {
        const int dr  = j * 32 + (t >> 3);
        const int sc0 = (t & 7) * 8;
        bf16x8 o;
#pragma unroll
        for (int e = 0; e < 8; e++) o[e] = tile[sc0 + e][dr];
        *(bf16x8*)(Vtb + (size_t)(d0 + dr) * 2048 + s0 + sc0) = o;
    }
}

// linv[row] = 1 / sum_k U[row][k],  row = b*2048+m, K=2048 (one 16B load/thread)
__global__ __launch_bounds__(256) void k_rowsum(
    const bf16_t* __restrict__ U, float* __restrict__ linv)
{
    __shared__ float red[256];
    const int row = blockIdx.x;
    const int t   = threadIdx.x;
    bf16x8 v = *((const bf16x8*)(U + (size_t)row * 2048) + t);
    float s = 0.f;
#pragma unroll
    for (int e = 0; e < 8; e++) s += (float)v[e];
    red[t] = s;
    __syncthreads();
    for (int o = 128; o > 0; o >>= 1) {
        if (t < o) red[t] += red[t + o];
        __syncthreads();
    }
    if (t == 0) linv[row] = 1.0f / red[0];
}

// ---------------------------------------------------------------------------

extern "C" void kernel_launch(void* const* d_in, const int* in_sizes, int n_in,
                              void* d_out, int out_size, void* d_ws, size_t ws_size,
                              hipStream_t stream)
{
    const float* x  = (const float*)d_in[0];
    const float* Wq = (const float*)d_in[1];
    const float* bq = (const float*)d_in[2];
    const float* Wk = (const float*)d_in[3];
    const float* bk = (const float*)d_in[4];
    const float* Wv = (const float*)d_in[5];
    const float* bv = (const float*)d_in[6];

    bf16_t* Q    = (bf16_t*)d_ws;              // 16384x1024
    bf16_t* Km   = Q + 16777216;               // 16384x1024
    bf16_t* Vt   = Km + 16777216;              // 8 x 1024x2048
    bf16_t* U    = Vt + 16777216;              // 8 x 2048x2048
    bf16_t* xb   = U;                          // alias: dead before U written
    bf16_t* V    = U + 16777216;               // alias: dead before U written
    bf16_t* Wb   = U + 33554432;               // 3 x 1024x1024
    float*  linv = (float*)(Wb + 3145728);     // 16384

    // 1. conversions
    k_cvt<<<dim3(2048), 256, 0, stream>>>(x, xb, 16777216 / 4);
    k_cvt<<<dim3(512), 256, 0, stream>>>(Wq, Wb, 1048576 / 4);
    k_cvt<<<dim3(512), 256, 0, stream>>>(Wk, Wb + 1048576, 1048576 / 4);
    k_cvt<<<dim3(512), 256, 0, stream>>>(Wv, Wb + 2097152, 1048576 / 4);
    // 2. QKV projection
    k_qkv<<<dim3(8, 128, 3), 256, 0, stream>>>(xb, Wb, Q, V, bq, bk, bv);
    // 3. V transpose
    k_trans<<<dim3(16, 32, 8), 256, 0, stream>>>(V, Vt);
    // 4. scores -> exp
    k_scores<<<dim3(16, 16, 8), 256, 0, stream>>>(Q, Km, U);
    // 5. row sums
    k_rowsum<<<dim3(16384), 256, 0, stream>>>(U, linv);
    // 6. PV + normalize
    k_pv<<<dim3(8, 16, 8), 256, 0, stream>>>(U, Vt, (float*)d_out, linv);
}

// Round 2
// 496.502 us; speedup vs baseline: 1.0291x; 1.0291x over previous
//
#include <hip/hip_runtime.h>
#include <stdint.h>

// Self-attention, B=8, S=2048, D=1024, fp32 in/out, bf16 MFMA compute.
//
// Pipeline (all on `stream`):
//   1. cvt: x -> xb (bf16); Wq/Wk/Wv -> Wb (bf16, one fused launch)
//   2. k_qkv  : Q/K/V = xb @ W^T + b          (GEMM_BT, grid.z=3, bf16 out)
//   3. k_trans: Vt[b][d][s] = V[b][s][d]      (so PV is K-contiguous GEMM_BT)
//   4. k_scores: U = exp((Q @ K^T)/32)        (bf16, no max-subtraction: scores
//                                              bounded |s|<=|q||k|/32 ~ O(10))
//   5. k_rowsum: linv[b,m] = 1 / sum_k U      (deterministic block reduce)
//   6. k_pv   : out = (U @ Vt^T) * linv       (fp32 out)
//
// R1 change: XCD-aware block swizzle on all GEMMs. HW round-robins consecutive
// workgroups across 8 XCDs; the 8 n-tiles sharing an A-strip were adjacent in
// dispatch order -> 8 different XCDs each fetched the strip into its own L2
// (399 MB FETCH vs 40 MB distinct in k_qkv). Swizzle puts sharers on the SAME
// XCD, temporally adjacent: xcd = lid&7, slot = lid>>3, x fast within slot.
//
// ws layout:
//   [0,       33.5M)  Q        16384x1024 bf16
//   [33.5M,   67.1M)  K        16384x1024 bf16
//   [67.1M,  100.7M)  Vt       8 x 1024x2048 bf16
//   [100.7M, 167.8M)  U        8 x 2048x2048 bf16   (first half aliases xb,
//        second half aliases V -- both dead before U written)
//   [167.8M, 174.1M)  Wb       3 x 1024x1024 bf16
//   [174.1M, ...)     linv     16384 fp32

typedef __bf16 bf16_t;
typedef __bf16 bf16x8 __attribute__((ext_vector_type(8)));
typedef __bf16 bf16x4 __attribute__((ext_vector_type(4)));
typedef float f32x4 __attribute__((ext_vector_type(4)));

__device__ __forceinline__ void gload_lds16(const bf16_t* g, bf16_t* l) {
    __builtin_amdgcn_global_load_lds((const __attribute__((address_space(1))) void*)g,
                                     (__attribute__((address_space(3))) void*)l,
                                     16, 0, 0);
}

// XCD-aware swizzle: blocks sharing an A-strip (same y) get the same lid%8
// (same XCD under round-robin dispatch) and adjacent slots (temporal reuse).
// NX, NY powers of two, NY % 8 == 0.
template <int NX, int NY, int LOGNX>
__device__ __forceinline__ void swz_xy(int& x, int& y) {
    const int lid  = blockIdx.x + NX * blockIdx.y;
    const int xcd  = lid & 7;
    const int slot = lid >> 3;
    x = slot & (NX - 1);
    y = xcd * (NY / 8) + (slot >> LOGNX);
}

// ---------------------------------------------------------------------------
// Core GEMM: C[M,N] = A[M,K] @ B[N,K]^T, both A,B bf16 row-major K-contiguous.
// Tile: 128x128, BK=64, 256 threads (4 waves, 2x2), 4x4 16x16x32 MFMAs/wave.
// EPI: 0 = +bias[col] -> bf16   (aux = bias, fp32)
//      1 = exp(acc*scale) -> bf16
//      2 = acc*aux[row] -> fp32  (aux = 1/l per row)
// ---------------------------------------------------------------------------
template <int EPI>
__device__ __forceinline__ void gemm_bt_core(
    const bf16_t* __restrict__ A, int lda,
    const bf16_t* __restrict__ B, int ldb,
    bf16_t* __restrict__ Cb, float* __restrict__ Cf, int ldc,
    const float* __restrict__ aux, float scale, int K,
    int m0, int n0)
{
    __shared__ bf16_t As[128 * 64];
    __shared__ bf16_t Bs[128 * 64];

    const int t    = threadIdx.x;
    const int lane = t & 63;
    const int wave = t >> 6;
    const int wm   = wave >> 1;
    const int wn   = wave & 1;
    const int lr   = lane & 15;
    const int quad = lane >> 4;

    const int srow   = t >> 3;
    const int schunk = (t & 7) * 8;

    f32x4 acc[4][4];
#pragma unroll
    for (int i = 0; i < 4; i++)
#pragma unroll
        for (int j = 0; j < 4; j++) acc[i][j] = (f32x4){0.f, 0.f, 0.f, 0.f};

    const bf16_t* Ag = A + (size_t)(m0 + srow) * lda + schunk;
    const bf16_t* Bg = B + (size_t)(n0 + srow) * ldb + schunk;

    for (int kt = 0; kt < K; kt += 64) {
#pragma unroll
        for (int j = 0; j < 4; j++) {
            gload_lds16(Ag + (size_t)j * 32 * lda + kt, As + j * 2048 + t * 8);
            gload_lds16(Bg + (size_t)j * 32 * ldb + kt, Bs + j * 2048 + t * 8);
        }
        __syncthreads();

#pragma unroll
        for (int s = 0; s < 2; s++) {
            bf16x8 af[4], bfr[4];
#pragma unroll
            for (int i = 0; i < 4; i++)
                af[i] = *(const bf16x8*)(As + (wm * 64 + i * 16 + lr) * 64 + s * 32 + quad * 8);
#pragma unroll
            for (int j = 0; j < 4; j++)
                bfr[j] = *(const bf16x8*)(Bs + (wn * 64 + j * 16 + lr) * 64 + s * 32 + quad * 8);
#pragma unroll
            for (int i = 0; i < 4; i++)
#pragma unroll
                for (int j = 0; j < 4; j++)
                    acc[i][j] = __builtin_amdgcn_mfma_f32_16x16x32_bf16(af[i], bfr[j], acc[i][j], 0, 0, 0);
        }
        __syncthreads();
    }

    // Epilogue. C/D layout: col = lane&15, row = quad*4 + reg.
    if (EPI == 0) {
#pragma unroll
        for (int j = 0; j < 4; j++) {
            const int col  = n0 + wn * 64 + j * 16 + lr;
            const float bv = aux[col];
#pragma unroll
            for (int i = 0; i < 4; i++) {
                const int row = m0 + wm * 64 + i * 16 + quad * 4;
#pragma unroll
                for (int r = 0; r < 4; r++)
                    Cb[(size_t)(row + r) * ldc + col] = (__bf16)(acc[i][j][r] + bv);
            }
        }
    } else if (EPI == 1) {
#pragma unroll
        for (int j = 0; j < 4; j++) {
            const int col = n0 + wn * 64 + j * 16 + lr;
#pragma unroll
            for (int i = 0; i < 4; i++) {
                const int row = m0 + wm * 64 + i * 16 + quad * 4;
#pragma unroll
                for (int r = 0; r < 4; r++)
                    Cb[(size_t)(row + r) * ldc + col] = (__bf16)__expf(acc[i][j][r] * scale);
            }
        }
    } else {
#pragma unroll
        for (int i = 0; i < 4; i++) {
            const int row = m0 + wm * 64 + i * 16 + quad * 4;
#pragma unroll
            for (int r = 0; r < 4; r++) {
                const float s = aux[row + r];
                float* crow = Cf + (size_t)(row + r) * ldc + n0 + wn * 64 + lr;
#pragma unroll
                for (int j = 0; j < 4; j++)
                    crow[j * 16] = acc[i][j][r] * s;
            }
        }
    }
}

// --------------------------- kernel wrappers -------------------------------

__global__ __launch_bounds__(256) void k_qkv(
    const bf16_t* __restrict__ xb, const bf16_t* __restrict__ Wb,
    bf16_t* __restrict__ Q, bf16_t* __restrict__ V,
    const float* __restrict__ bq, const float* __restrict__ bk,
    const float* __restrict__ bv)
{
    const int z = blockIdx.z;
    const float* bias = (z == 0) ? bq : (z == 1) ? bk : bv;
    bf16_t* C = (z == 2) ? V : Q + (size_t)z * 16384 * 1024;
    int x, y;
    swz_xy<8, 128, 3>(x, y);
    gemm_bt_core<0>(xb, 1024, Wb + (size_t)z * 1024 * 1024, 1024,
                    C, nullptr, 1024, bias, 0.f, 1024, y * 128, x * 128);
}

__global__ __launch_bounds__(256) void k_scores(
    const bf16_t* __restrict__ Q, const bf16_t* __restrict__ Km,
    bf16_t* __restrict__ U)
{
    const int b = blockIdx.z;
    int x, y;
    swz_xy<16, 16, 4>(x, y);
    gemm_bt_core<1>(Q + (size_t)b * 2048 * 1024, 1024,
                    Km + (size_t)b * 2048 * 1024, 1024,
                    U + (size_t)b * 2048 * 2048, nullptr, 2048,
                    nullptr, 0.03125f, 1024, y * 128, x * 128);
}

__global__ __launch_bounds__(256) void k_pv(
    const bf16_t* __restrict__ U, const bf16_t* __restrict__ Vt,
    float* __restrict__ Out, const float* __restrict__ linv)
{
    const int b = blockIdx.z;
    int x, y;
    swz_xy<8, 16, 3>(x, y);
    gemm_bt_core<2>(U + (size_t)b * 2048 * 2048, 2048,
                    Vt + (size_t)b * 1024 * 2048, 2048,
                    nullptr, Out + (size_t)b * 2048 * 1024, 1024,
                    linv + b * 2048, 0.f, 2048, y * 128, x * 128);
}

// fp32 -> bf16 conversion, 4 elems/thread, grid-stride
__global__ __launch_bounds__(256) void k_cvt(
    const float* __restrict__ in, bf16_t* __restrict__ out, long ngroups)
{
    long idx    = (long)blockIdx.x * blockDim.x + threadIdx.x;
    long stride = (long)gridDim.x * blockDim.x;
    for (long i = idx; i < ngroups; i += stride) {
        float4 v = ((const float4*)in)[i];
        bf16x4 o = { (__bf16)v.x, (__bf16)v.y, (__bf16)v.z, (__bf16)v.w };
        ((bf16x4*)out)[i] = o;
    }
}

// fused 3-weight fp32 -> bf16 (z selects source), 1048576 elems each
__global__ __launch_bounds__(256) void k_cvt3(
    const float* __restrict__ w0, const float* __restrict__ w1,
    const float* __restrict__ w2, bf16_t* __restrict__ out)
{
    const int z = blockIdx.z;
    const float* in = (z == 0) ? w0 : (z == 1) ? w1 : w2;
    bf16_t* o = out + (size_t)z * 1048576;
    long i = (long)blockIdx.x * blockDim.x + threadIdx.x;   // 1024 blocks x 256
    float4 v = ((const float4*)in)[i];
    bf16x4 ov = { (__bf16)v.x, (__bf16)v.y, (__bf16)v.z, (__bf16)v.w };
    ((bf16x4*)o)[i] = ov;
}

// V (8 x 2048 x 1024) -> Vt (8 x 1024 x 2048), 64x64 LDS tiles
__global__ __launch_bounds__(256) void k_trans(
    const bf16_t* __restrict__ V, bf16_t* __restrict__ Vt)
{
    __shared__ bf16_t tile[64][66];
    const int b  = blockIdx.z;
    const int d0 = blockIdx.x * 64;
    const int s0 = blockIdx.y * 64;
    const bf16_t* Vb = V + (size_t)b * 2048 * 1024;
    bf16_t* Vtb      = Vt + (size_t)b * 1024 * 2048;
    const int t = threadIdx.x;

#pragma unroll
    for (int j = 0; j < 2; j++) {
        const int r = j * 32 + (t >> 3);
        const int c = (t & 7) * 8;
        bf16x8 v = *(const bf16x8*)(Vb + (size_t)(s0 + r) * 1024 + d0 + c);
#pragma unroll
        for (int e = 0; e < 8; e++) tile[r][c + e] = v[e];
    }
    __syncthreads();
#pragma unroll
    for (int j = 0; j < 2; j++) {
        const int dr  = j * 32 + (t >> 3);
        const int sc0 = (t & 7) * 8;
        bf16x8 o;
#pragma unroll
        for (int e = 0; e < 8; e++) o[e] = tile[sc0 + e][dr];
        *(bf16x8*)(Vtb + (size_t)(d0 + dr) * 2048 + s0 + sc0) = o;
    }
}

// linv[row] = 1 / sum_k U[row][k],  K=2048 (one 16B load/thread)
__global__ __launch_bounds__(256) void k_rowsum(
    const bf16_t* __restrict__ U, float* __restrict__ linv)
{
    __shared__ float red[256];
    const int row = blockIdx.x;
    const int t   = threadIdx.x;
    bf16x8 v = *((const bf16x8*)(U + (size_t)row * 2048) + t);
    float s = 0.f;
#pragma unroll
    for (int e = 0; e < 8; e++) s += (float)v[e];
    red[t] = s;
    __syncthreads();
    for (int o = 128; o > 0; o >>= 1) {
        if (t < o) red[t] += red[t + o];
        __syncthreads();
    }
    if (t == 0) linv[row] = 1.0f / red[0];
}

// ---------------------------------------------------------------------------

extern "C" void kernel_launch(void* const* d_in, const int* in_sizes, int n_in,
                              void* d_out, int out_size, void* d_ws, size_t ws_size,
                              hipStream_t stream)
{
    const float* x  = (const float*)d_in[0];
    const float* Wq = (const float*)d_in[1];
    const float* bq = (const float*)d_in[2];
    const float* Wk = (const float*)d_in[3];
    const float* bk = (const float*)d_in[4];
    const float* Wv = (const float*)d_in[5];
    const float* bv = (const float*)d_in[6];

    bf16_t* Q    = (bf16_t*)d_ws;              // 16384x1024
    bf16_t* Km   = Q + 16777216;               // 16384x1024
    bf16_t* Vt   = Km + 16777216;              // 8 x 1024x2048
    bf16_t* U    = Vt + 16777216;              // 8 x 2048x2048
    bf16_t* xb   = U;                          // alias: dead before U written
    bf16_t* V    = U + 16777216;               // alias: dead before U written
    bf16_t* Wb   = U + 33554432;               // 3 x 1024x1024
    float*  linv = (float*)(Wb + 3145728);     // 16384

    // 1. conversions
    k_cvt<<<dim3(2048), 256, 0, stream>>>(x, xb, 16777216 / 4);
    k_cvt3<<<dim3(1024, 1, 3), 256, 0, stream>>>(Wq, Wk, Wv, Wb);
    // 2. QKV projection
    k_qkv<<<dim3(8, 128, 3), 256, 0, stream>>>(xb, Wb, Q, V, bq, bk, bv);
    // 3. V transpose
    k_trans<<<dim3(16, 32, 8), 256, 0, stream>>>(V, Vt);
    // 4. scores -> exp
    k_scores<<<dim3(16, 16, 8), 256, 0, stream>>>(Q, Km, U);
    // 5. row sums
    k_rowsum<<<dim3(16384), 256, 0, stream>>>(U, linv);
    // 6. PV + normalize
    k_pv<<<dim3(8, 16, 8), 256, 0, stream>>>(U, Vt, (float*)d_out, linv);
}